// Round 3
// baseline (11328.315 us; speedup 1.0000x reference)
//
#include <hip/hip_runtime.h>
#include <hip/hip_bf16.h>
#include <math.h>

// ---------------------------------------------------------------------------
// BabiUTransformer (Universal Transformer + ACT) on gfx950.
// ALL float I/O is fp32 (evidence: round-2 NaN from bf16-misread + 1.2e-4-rel
// tolerance impossible under bf16 output quantization). int inputs int32.
// GEMMs: split-precision bf16 MFMA — A split hi/lo on the fly, weights
// pre-split into hi/lo bf16 planes, 3 MFMAs (hh+lh+hl), error ~2^-18 rel.
// ACT any()-gate implemented faithfully via per-step device flag.
// Convs as dense im2col GEMMs with validity-masked staging (no pad rows).
// Workspace ~243 MiB.
// ---------------------------------------------------------------------------

typedef unsigned short ushort_t;
using short8  = __attribute__((ext_vector_type(8))) short;
using floatx4 = __attribute__((ext_vector_type(4))) float;

#define B_   256
#define L_   71
#define H_   512
#define M_   (B_*L_)      // 18176 rows (284 x 64); half = 9088 (142 x 64)
#define MH_  9088
#define FS_  2048
#define V_   32000
#define NH_  8
#define DK_  64

__device__ inline ushort_t f2bf_rne(float f) {
    unsigned u = __float_as_uint(f);
    return (ushort_t)((u + 0x7FFFu + ((u >> 16) & 1u)) >> 16);
}

// ---------------------------------------------------------------------------
// Split GEMM: C[M,N] = alpha*(A_f32 @ B) (+bias)(+residual)(relu)(+prev upd)
// B given as hi/lo bf16 planes [N,K] row-major (ldb == K).
// conv=1: A is dense [rows, lda]; row m's window starts at A row (am+rowA-1);
//   chunk with d==0 invalid when l==0, d==2 invalid when l==70 (zero-filled).
// rowC: global row offset for C/residual/uw/prev. rowG: offset for l.
// ---------------------------------------------------------------------------
__global__ __launch_bounds__(256) void gemm_s(
    const float* __restrict__ A, int lda, int conv, int rowA, int rowG,
    const ushort_t* __restrict__ Bh, const ushort_t* __restrict__ Bl,
    int N, int K,
    const float* __restrict__ bias, const float* residual,
    float alpha, int relu, int rowC,
    float* Cout, float* prev, const float* __restrict__ uw)
{
    __shared__ short Ah[2560], Al[2560], Bhs[2560], Bls[2560];
    const int tid  = threadIdx.x;
    const int wave = tid >> 6, lane = tid & 63;
    const int bm = blockIdx.y << 6, bn = blockIdx.x << 6;
    const int wr = (wave >> 1) << 5, wc = (wave & 1) << 5;

    floatx4 acc[2][2] = {};

    const int rowL = tid >> 2;           // 0..63
    const int ak   = (tid & 3) << 3;     // 0,8,16,24
    const int am   = bm + rowL;
    const float* Ap;
    int l = 0;
    if (conv) {
        l  = (am + rowG) % 71;
        Ap = A + (long)(am + rowA - 1) * lda + ak;
    } else {
        Ap = A + (long)(am + rowA) * lda + ak;
    }
    const long bgoff = (long)(bn + rowL) * K + ak;
    const int woff = rowL * 40 + ak;

    const int quad = lane >> 4, mr = lane & 15;
    const int aoff0 = (wr + mr) * 40 + quad * 8, aoff1 = aoff0 + 640;
    const int boff0 = (wc + mr) * 40 + quad * 8, boff1 = boff0 + 640;

    for (int k0 = 0; k0 < K; k0 += 32) {
        float4 f0 = {0.f,0.f,0.f,0.f}, f1 = {0.f,0.f,0.f,0.f};
        bool valid = true;
        if (conv) {
            int kk = ak + k0;
            int d = (kk >= lda) ? ((kk >= 2 * lda) ? 2 : 1) : 0;
            valid = !((l == 0 && d == 0) || (l == 70 && d == 2));
        }
        if (valid) {
            f0 = *(const float4*)(Ap + k0);
            f1 = *(const float4*)(Ap + k0 + 4);
        }
        uint4 bh = *(const uint4*)(Bh + bgoff + k0);
        uint4 bl = *(const uint4*)(Bl + bgoff + k0);
        float fv[8] = {f0.x, f0.y, f0.z, f0.w, f1.x, f1.y, f1.z, f1.w};
        short8 hv, lv;
        #pragma unroll
        for (int j = 0; j < 8; j++) {
            ushort_t h = f2bf_rne(fv[j]);
            float hf = __uint_as_float(((unsigned)h) << 16);
            hv[j] = (short)h;
            lv[j] = (short)f2bf_rne(fv[j] - hf);
        }
        __syncthreads();
        *(short8*)(Ah + woff)  = hv;
        *(short8*)(Al + woff)  = lv;
        *(uint4*)(Bhs + woff)  = bh;
        *(uint4*)(Bls + woff)  = bl;
        __syncthreads();
        short8 ah0 = *(const short8*)(Ah + aoff0), ah1 = *(const short8*)(Ah + aoff1);
        short8 al0 = *(const short8*)(Al + aoff0), al1 = *(const short8*)(Al + aoff1);
        short8 bh0 = *(const short8*)(Bhs + boff0), bh1 = *(const short8*)(Bhs + boff1);
        short8 bl0 = *(const short8*)(Bls + boff0), bl1 = *(const short8*)(Bls + boff1);
        acc[0][0] = __builtin_amdgcn_mfma_f32_16x16x32_bf16(ah0, bh0, acc[0][0], 0, 0, 0);
        acc[0][0] = __builtin_amdgcn_mfma_f32_16x16x32_bf16(al0, bh0, acc[0][0], 0, 0, 0);
        acc[0][0] = __builtin_amdgcn_mfma_f32_16x16x32_bf16(ah0, bl0, acc[0][0], 0, 0, 0);
        acc[0][1] = __builtin_amdgcn_mfma_f32_16x16x32_bf16(ah0, bh1, acc[0][1], 0, 0, 0);
        acc[0][1] = __builtin_amdgcn_mfma_f32_16x16x32_bf16(al0, bh1, acc[0][1], 0, 0, 0);
        acc[0][1] = __builtin_amdgcn_mfma_f32_16x16x32_bf16(ah0, bl1, acc[0][1], 0, 0, 0);
        acc[1][0] = __builtin_amdgcn_mfma_f32_16x16x32_bf16(ah1, bh0, acc[1][0], 0, 0, 0);
        acc[1][0] = __builtin_amdgcn_mfma_f32_16x16x32_bf16(al1, bh0, acc[1][0], 0, 0, 0);
        acc[1][0] = __builtin_amdgcn_mfma_f32_16x16x32_bf16(ah1, bl0, acc[1][0], 0, 0, 0);
        acc[1][1] = __builtin_amdgcn_mfma_f32_16x16x32_bf16(ah1, bh1, acc[1][1], 0, 0, 0);
        acc[1][1] = __builtin_amdgcn_mfma_f32_16x16x32_bf16(al1, bh1, acc[1][1], 0, 0, 0);
        acc[1][1] = __builtin_amdgcn_mfma_f32_16x16x32_bf16(ah1, bl1, acc[1][1], 0, 0, 0);
    }

    // C/D layout: col = lane&15, row = quad*4 + r  [verified m89/m91]
    #pragma unroll
    for (int ti = 0; ti < 2; ti++)
    #pragma unroll
    for (int tj = 0; tj < 2; tj++) {
        int gcol = bn + wc + tj * 16 + mr;
        float bv = bias ? bias[gcol] : 0.f;
        #pragma unroll
        for (int r = 0; r < 4; r++) {
            int grow = bm + wr + ti * 16 + quad * 4 + r;
            long crow = (long)grow + rowC;
            float v = acc[ti][tj][r] * alpha + bv;
            if (residual) v += residual[crow * N + gcol];
            if (relu) v = fmaxf(v, 0.f);
            long cidx = crow * (long)N + gcol;
            Cout[cidx] = v;
            if (prev) {
                float u = uw[crow];
                prev[cidx] = v * u + prev[cidx] * (1.f - u);
            }
        }
    }
}

// ---------------------------------------------------------------------------
// Timing-signal tables, float32 math to match numpy's float32 exp/sin chain.
// ---------------------------------------------------------------------------
__global__ __launch_bounds__(256) void sig_prep(float* __restrict__ T, float* __restrict__ P)
{
    int i = blockIdx.x * 256 + threadIdx.x;
    const int NT = 71 * 512;
    if (i >= NT + 6 * 512) return;
    int pos, c, idx;
    float* dst;
    if (i < NT) { pos = i >> 9; c = i & 511; dst = T; idx = i; }
    else        { int j = i - NT; pos = j >> 9; c = j & 511; dst = P; idx = j; }
    const float loginc = 0.036119766f;   // fl32(log(1e4)/255)
    int jj = c & 255;
    float inv = expf(-(float)jj * loginc);
    float arg = (float)pos * inv;
    dst[idx] = (c < 256) ? sinf(arg) : cosf(arg);
}

// active-gate: flag |= any(hp<0.9 && nu<6)
__global__ __launch_bounds__(256) void gate_kernel(
    const float* __restrict__ hp, const float* __restrict__ nu, int* __restrict__ flag)
{
    int i = blockIdx.x * 256 + threadIdx.x;
    if (i < M_ && hp[i] < 0.9f && nu[i] < 6.0f) atomicOr(flag, 1);
}

// ---------------------------------------------------------------------------
// s = state + T[l] + P[t] (in-place); pr = sigmoid(s.p_w+p_b); gated ACT.
// ---------------------------------------------------------------------------
__global__ __launch_bounds__(256) void s_pr_kernel(
    float* trunk, const float* __restrict__ Ttab, const float* __restrict__ Ptab,
    const float* __restrict__ p_w, const float* __restrict__ p_b,
    float* __restrict__ hp, float* __restrict__ rem, float* __restrict__ nu,
    float* __restrict__ uw, const int* __restrict__ flag, int t)
{
    const int row  = blockIdx.x * 4 + (threadIdx.x >> 6);
    const int lane = threadIdx.x & 63;
    const int l    = row % 71;
    float dot = 0.f;
    #pragma unroll
    for (int j = 0; j < 8; j++) {
        int c  = lane + 64 * j;
        float sv = trunk[(long)row * H_ + c] + Ttab[l * H_ + c] + Ptab[t * H_ + c];
        trunk[(long)row * H_ + c] = sv;
        dot += sv * p_w[c];
    }
    #pragma unroll
    for (int o = 32; o; o >>= 1) dot += __shfl_xor(dot, o);
    if (lane == 0) {
        if (flag[0]) {
            float pr = 1.f / (1.f + expf(-(dot + p_b[0])));
            float hp0 = hp[row], rem0 = rem[row], nu0 = nu[row];
            float still = (hp0 < 1.0f) ? 1.f : 0.f;
            float tot   = hp0 + pr * still;
            float nh    = ((tot > 0.9f) ? 1.f : 0.f) * still;
            float st2   = ((tot <= 0.9f) ? 1.f : 0.f) * still;
            float hp2   = hp0 + pr * st2;
            float rem2  = rem0 + nh * (1.f - hp2);
            hp2 += nh * rem2;
            hp[row] = hp2; rem[row] = rem2; nu[row] = nu0 + st2 + nh;
            uw[row] = pr * st2 + nh * rem2;
        } else {
            uw[row] = 0.f;   // frozen: prev-update becomes a no-op
        }
    }
}

// LayerNorm fp32 (mean, std ddof=1, /(sd+1e-6))
__global__ __launch_bounds__(256) void ln_kernel(
    const float* __restrict__ X, const float* __restrict__ g,
    const float* __restrict__ bb, float* __restrict__ out)
{
    const int row  = blockIdx.x * 4 + (threadIdx.x >> 6);
    const int lane = threadIdx.x & 63;
    const float* xr = X + (long)row * H_;
    float v[8];
    float s = 0.f;
    #pragma unroll
    for (int j = 0; j < 8; j++) { v[j] = xr[lane + 64 * j]; s += v[j]; }
    #pragma unroll
    for (int o = 32; o; o >>= 1) s += __shfl_xor(s, o);
    float mean = s * (1.f / 512.f);
    float q = 0.f;
    #pragma unroll
    for (int j = 0; j < 8; j++) { float d = v[j] - mean; q += d * d; }
    #pragma unroll
    for (int o = 32; o; o >>= 1) q += __shfl_xor(q, o);
    float sd  = sqrtf(q * (1.f / 511.f));
    float inv = 1.f / (sd + 1e-6f);
    #pragma unroll
    for (int j = 0; j < 8; j++) {
        int c = lane + 64 * j;
        out[(long)row * H_ + c] = g[c] * (v[j] - mean) * inv + bb[c];
    }
}

// Attention, fp32. One block per (b,h). q pre-scaled by 1/8.
__global__ __launch_bounds__(256) void attn_kernel(
    const float* __restrict__ q, const float* __restrict__ k,
    const float* __restrict__ v, float* __restrict__ ctx)
{
    __shared__ float qs[L_ * DK_];
    __shared__ float ks[L_ * DK_];   // reused for V
    __shared__ float Ss[L_ * 72];
    const int tid = threadIdx.x;
    const int b = blockIdx.x >> 3, h = blockIdx.x & 7;
    const long base = (long)b * L_ * H_ + h * DK_;
    for (int idx = tid; idx < L_ * DK_; idx += 256) {
        int i = idx >> 6, d = idx & 63;
        qs[idx] = q[base + (long)i * H_ + d];
        ks[idx] = k[base + (long)i * H_ + d];
    }
    __syncthreads();
    for (int idx = tid; idx < L_ * L_; idx += 256) {
        int i = idx / 71, j = idx % 71;
        float s = 0.f;
        #pragma unroll 8
        for (int d = 0; d < 64; d++) s += qs[i * 64 + d] * ks[j * 64 + d];
        Ss[i * 72 + j] = s;
    }
    __syncthreads();
    if (tid < L_) {
        float mx = -1e30f;
        for (int j = 0; j < L_; j++) mx = fmaxf(mx, Ss[tid * 72 + j]);
        float sm = 0.f;
        for (int j = 0; j < L_; j++) { float e = expf(Ss[tid * 72 + j] - mx); Ss[tid * 72 + j] = e; sm += e; }
        float inv = 1.f / sm;
        for (int j = 0; j < L_; j++) Ss[tid * 72 + j] *= inv;
    }
    for (int idx = tid; idx < L_ * DK_; idx += 256) {
        int i = idx >> 6, d = idx & 63;
        ks[idx] = v[base + (long)i * H_ + d];
    }
    __syncthreads();
    for (int idx = tid; idx < L_ * DK_; idx += 256) {
        int i = idx >> 6, d = idx & 63;
        float s = 0.f;
        for (int j = 0; j < L_; j++) s += Ss[i * 72 + j] * ks[j * 64 + d];
        ctx[base + (long)i * H_ + d] = s;
    }
}

// Embedding: x[b,m,:] = sum_s emb[idx_s,:]*mask[s,:]
__global__ __launch_bounds__(256) void embed_kernel(
    const int* __restrict__ story, const int* __restrict__ query,
    const float* __restrict__ emb, const float* __restrict__ mask,
    float* __restrict__ x)
{
    __shared__ int idx[11];
    const int row = blockIdx.x;
    const int b = row / 71, m = row % 71;
    const int tid = threadIdx.x;
    if (tid < 11)
        idx[tid] = (m < 70) ? story[((long)b * 70 + m) * 11 + tid]
                            : query[(long)b * 11 + tid];
    __syncthreads();
    for (int c = tid; c < H_; c += 256) {
        float acc = 0.f;
        #pragma unroll
        for (int s = 0; s < 11; s++)
            acc += emb[(long)idx[s] * H_ + c] * mask[s * H_ + c];
        x[(long)row * H_ + c] = acc;
    }
}

// transpose + split fp32 [R,C] -> bf16 hi/lo planes [C,R]
__global__ __launch_bounds__(256) void wsplitT_kernel(
    const float* __restrict__ in, ushort_t* __restrict__ hi, ushort_t* __restrict__ lo,
    int R, int C)
{
    long i = (long)blockIdx.x * 256 + threadIdx.x;
    if (i < (long)R * C) {
        int r = (int)(i / C), c = (int)(i % C);
        float f = in[i];
        ushort_t h = f2bf_rne(f);
        float hf = __uint_as_float(((unsigned)h) << 16);
        hi[(long)c * R + r] = h;
        lo[(long)c * R + r] = f2bf_rne(f - hf);
    }
}

// conv weight gather+split: plane[n*(3C) + d*C + c] = w[(n*C + c)*3 + d]
__global__ __launch_bounds__(256) void convw_split_kernel(
    const float* __restrict__ w, ushort_t* __restrict__ hi, ushort_t* __restrict__ lo,
    int N, int C)
{
    long i = (long)blockIdx.x * 256 + threadIdx.x;
    if (i < (long)N * C * 3) {
        int n = (int)(i / (3 * C));
        int r = (int)(i % (3 * C));
        int d = r / C, c = r % C;
        float f = w[((long)n * C + c) * 3 + d];
        ushort_t h = f2bf_rne(f);
        float hf = __uint_as_float(((unsigned)h) << 16);
        hi[i] = h;
        lo[i] = f2bf_rne(f - hf);
    }
}

// plain split (no transpose): emb [V,E] -> hi/lo planes same layout
__global__ __launch_bounds__(256) void esplit_kernel(
    const float* __restrict__ in, ushort_t* __restrict__ hi, ushort_t* __restrict__ lo,
    long n)
{
    long i = (long)blockIdx.x * 256 + threadIdx.x;
    if (i < n) {
        float f = in[i];
        ushort_t h = f2bf_rne(f);
        float hf = __uint_as_float(((unsigned)h) << 16);
        hi[i] = h;
        lo[i] = f2bf_rne(f - hf);
    }
}

__global__ __launch_bounds__(256) void zero_f32(float* __restrict__ p, long n)
{
    long i = (long)blockIdx.x * 256 + threadIdx.x;
    if (i < n) p[i] = 0.f;
}

// pooled[b,c] = (sum_l prev[b,l,c]) / 71
__global__ __launch_bounds__(256) void pooled_kernel(
    const float* __restrict__ prev, float* __restrict__ pooled)
{
    int i = blockIdx.x * 256 + threadIdx.x;   // [0, 256*512)
    int b = i >> 9, c = i & 511;
    float s = 0.f;
    for (int l = 0; l < L_; l++) s += prev[((long)b * L_ + l) * H_ + c];
    pooled[i] = s / 71.0f;
}

__global__ __launch_bounds__(256) void softmax_kernel(
    const float* __restrict__ ah, float* __restrict__ out)
{
    __shared__ float red[256];
    const int b = blockIdx.x, tid = threadIdx.x;
    const float* a = ah + (long)b * V_;
    float mx = -1e30f;
    for (int i = tid; i < V_; i += 256) mx = fmaxf(mx, a[i]);
    red[tid] = mx; __syncthreads();
    for (int o = 128; o; o >>= 1) { if (tid < o) red[tid] = fmaxf(red[tid], red[tid + o]); __syncthreads(); }
    mx = red[0]; __syncthreads();
    float s = 0.f;
    for (int i = tid; i < V_; i += 256) s += expf(a[i] - mx);
    red[tid] = s; __syncthreads();
    for (int o = 128; o; o >>= 1) { if (tid < o) red[tid] += red[tid + o]; __syncthreads(); }
    float inv = 1.f / red[0];
    float* o_ = out + (long)b * V_;
    for (int i = tid; i < V_; i += 256) o_[i] = expf(a[i] - mx) * inv;
}

__global__ __launch_bounds__(256) void tails_kernel(
    const float* __restrict__ rem, const float* __restrict__ nu, float* __restrict__ out)
{
    int i = blockIdx.x * 256 + threadIdx.x;
    if (i < M_) {
        out[i] = rem[i];
        out[M_ + i] = nu[i];
    }
}

// ---------------------------------------------------------------------------
extern "C" void kernel_launch(void* const* d_in, const int* in_sizes, int n_in,
                              void* d_out, int out_size, void* d_ws, size_t ws_size,
                              hipStream_t stream)
{
    const int*   story  = (const int*)d_in[0];
    const int*   query  = (const int*)d_in[1];
    const float* emb    = (const float*)d_in[2];
    const float* mask_p = (const float*)d_in[3];
    const float* proj_w = (const float*)d_in[4];
    const float* ln1_g  = (const float*)d_in[5];
    const float* ln1_b  = (const float*)d_in[6];
    const float* wq     = (const float*)d_in[7];
    const float* wk     = (const float*)d_in[8];
    const float* wv     = (const float*)d_in[9];
    const float* wo     = (const float*)d_in[10];
    const float* c1_w   = (const float*)d_in[11];
    const float* c1_b   = (const float*)d_in[12];
    const float* c2_w   = (const float*)d_in[13];
    const float* c2_b   = (const float*)d_in[14];
    const float* ln2_g  = (const float*)d_in[15];
    const float* ln2_b  = (const float*)d_in[16];
    const float* p_w    = (const float*)d_in[17];
    const float* p_b    = (const float*)d_in[18];
    const float* out_b  = (const float*)d_in[19];
    float* outp = (float*)d_out;

    char* wsb = (char*)d_ws;
    size_t off = 0;
    auto alloc = [&](size_t bytes) -> void* {
        void* p = wsb + off;
        off = (off + bytes + 255) & ~(size_t)255;
        return p;
    };
    const long ROWE = (long)M_ * H_;             // 9,306,112 elements

    float* trunkF = (float*)alloc(ROWE * 4);
    float* prevF  = (float*)alloc(ROWE * 4);
    char*  poolC  = (char*)alloc(4L * ROWE * 4); // 148.9 MB multi-purpose pool
    float* hpF    = (float*)alloc((long)M_ * 4 * 4 + 64);  // hp,rem,nu,uw + flags
    float* remF   = hpF + M_;
    float* nuF    = hpF + 2 * M_;
    float* uwF    = hpF + 3 * M_;
    int*   flags  = (int*)(hpF + 4 * M_);        // 6 step flags
    ushort_t* projH = (ushort_t*)alloc((long)H_ * H_ * 2);
    ushort_t* projL = (ushort_t*)alloc((long)H_ * H_ * 2);
    ushort_t* wqH   = (ushort_t*)alloc((long)H_ * H_ * 2);
    ushort_t* wqL   = (ushort_t*)alloc((long)H_ * H_ * 2);
    ushort_t* wkH   = (ushort_t*)alloc((long)H_ * H_ * 2);
    ushort_t* wkL   = (ushort_t*)alloc((long)H_ * H_ * 2);
    ushort_t* wvH   = (ushort_t*)alloc((long)H_ * H_ * 2);
    ushort_t* wvL   = (ushort_t*)alloc((long)H_ * H_ * 2);
    ushort_t* woH   = (ushort_t*)alloc((long)H_ * H_ * 2);
    ushort_t* woL   = (ushort_t*)alloc((long)H_ * H_ * 2);
    ushort_t* W1H   = (ushort_t*)alloc((long)FS_ * 3 * H_ * 2);
    ushort_t* W1L   = (ushort_t*)alloc((long)FS_ * 3 * H_ * 2);
    ushort_t* W2H   = (ushort_t*)alloc((long)H_ * 3 * FS_ * 2);
    ushort_t* W2L   = (ushort_t*)alloc((long)H_ * 3 * FS_ * 2);
    float* pooledF  = (float*)alloc((long)B_ * H_ * 4);
    float* Ttab     = (float*)alloc((long)L_ * H_ * 4);
    float* Ptab     = (float*)alloc(6L * H_ * 4);

    // pool aliases (phases are disjoint in time):
    float* qbF   = (float*)poolC;                   // [M,512]
    float* kbF   = qbF + ROWE;
    float* vbF   = qbF + 2 * ROWE;
    float* xnF   = qbF + 3 * ROWE;                  // LN1 out, then ctx
    float* xn2F  = qbF;                             // LN2 out dense [M,512]
    float* y1F   = qbF + ROWE;                      // conv1 out, half [9088,2048]
    float* xembF = qbF;                             // embedding (pre-loop)
    ushort_t* embH = (ushort_t*)poolC;              // post-loop emb planes
    ushort_t* embL = (ushort_t*)(poolC + (long)V_ * H_ * 2);

    dim3 blk(256);

    // --- init (ws re-poisoned every call) ---
    zero_f32<<<dim3((unsigned)((ROWE + 255) / 256)), blk, 0, stream>>>(prevF, ROWE);
    zero_f32<<<dim3((3 * M_ + 255) / 256), blk, 0, stream>>>(hpF, 3 * M_);
    zero_f32<<<dim3(1), blk, 0, stream>>>((float*)flags, 16);
    sig_prep<<<dim3(154), blk, 0, stream>>>(Ttab, Ptab);

    // --- weight prep: transpose + hi/lo split ---
    wsplitT_kernel<<<dim3(1024), blk, 0, stream>>>(proj_w, projH, projL, H_, H_);
    wsplitT_kernel<<<dim3(1024), blk, 0, stream>>>(wq, wqH, wqL, H_, H_);
    wsplitT_kernel<<<dim3(1024), blk, 0, stream>>>(wk, wkH, wkL, H_, H_);
    wsplitT_kernel<<<dim3(1024), blk, 0, stream>>>(wv, wvH, wvL, H_, H_);
    wsplitT_kernel<<<dim3(1024), blk, 0, stream>>>(wo, woH, woL, H_, H_);
    convw_split_kernel<<<dim3(12288), blk, 0, stream>>>(c1_w, W1H, W1L, FS_, H_);
    convw_split_kernel<<<dim3(12288), blk, 0, stream>>>(c2_w, W2H, W2L, H_, FS_);

    // --- embedding + input projection ---
    embed_kernel<<<dim3(M_), blk, 0, stream>>>(story, query, emb, mask_p, xembF);
    gemm_s<<<dim3(H_ / 64, M_ / 64), blk, 0, stream>>>(
        xembF, H_, 0, 0, 0, projH, projL, H_, H_,
        nullptr, nullptr, 1.f, 0, 0, trunkF, nullptr, nullptr);

    // --- ACT loop: 6 steps with faithful any()-gate ---
    for (int t = 0; t < 6; t++) {
        gate_kernel<<<dim3(M_ / 256), blk, 0, stream>>>(hpF, nuF, flags + t);
        s_pr_kernel<<<dim3(M_ / 4), blk, 0, stream>>>(trunkF, Ttab, Ptab, p_w, p_b,
                                                      hpF, remF, nuF, uwF, flags + t, t);
        ln_kernel<<<dim3(M_ / 4), blk, 0, stream>>>(trunkF, ln1_g, ln1_b, xnF);
        gemm_s<<<dim3(H_ / 64, M_ / 64), blk, 0, stream>>>(
            xnF, H_, 0, 0, 0, wqH, wqL, H_, H_,
            nullptr, nullptr, 0.125f, 0, 0, qbF, nullptr, nullptr);
        gemm_s<<<dim3(H_ / 64, M_ / 64), blk, 0, stream>>>(
            xnF, H_, 0, 0, 0, wkH, wkL, H_, H_,
            nullptr, nullptr, 1.f, 0, 0, kbF, nullptr, nullptr);
        gemm_s<<<dim3(H_ / 64, M_ / 64), blk, 0, stream>>>(
            xnF, H_, 0, 0, 0, wvH, wvL, H_, H_,
            nullptr, nullptr, 1.f, 0, 0, vbF, nullptr, nullptr);
        attn_kernel<<<dim3(B_ * NH_), blk, 0, stream>>>(qbF, kbF, vbF, xnF);  // ctx -> xnF
        gemm_s<<<dim3(H_ / 64, M_ / 64), blk, 0, stream>>>(
            xnF, H_, 0, 0, 0, woH, woL, H_, H_,
            nullptr, trunkF, 1.f, 0, 0, trunkF, nullptr, nullptr);  // x2 = s + wo*ctx
        ln_kernel<<<dim3(M_ / 4), blk, 0, stream>>>(trunkF, ln2_g, ln2_b, xn2F);
        for (int half = 0; half < 2; half++) {
            int ro = half * MH_;
            // conv1: A=xn2 dense (global rows), out y1 half-local, relu+bias
            gemm_s<<<dim3(FS_ / 64, MH_ / 64), blk, 0, stream>>>(
                xn2F, H_, 1, ro, ro, W1H, W1L, FS_, 3 * H_,
                c1_b, nullptr, 1.f, 1, 0, y1F, nullptr, nullptr);
            // conv2: A=y1 half-local, out trunk global + residual + prev update
            gemm_s<<<dim3(H_ / 64, MH_ / 64), blk, 0, stream>>>(
                y1F, FS_, 1, 0, ro, W2H, W2L, H_, 3 * FS_,
                c2_b, trunkF, 1.f, 0, ro, trunkF, prevF, uwF);
        }
    }

    // --- output head ---
    pooled_kernel<<<dim3(B_ * H_ / 256), blk, 0, stream>>>(prevF, pooledF);
    esplit_kernel<<<dim3(64000), blk, 0, stream>>>(emb, embH, embL, (long)V_ * H_);
    gemm_s<<<dim3(V_ / 64, B_ / 64), blk, 0, stream>>>(
        pooledF, H_, 0, 0, 0, embH, embL, V_, H_,
        out_b, nullptr, 1.f, 0, 0, outp, nullptr, nullptr);   // a_hat -> out[0:...]
    softmax_kernel<<<dim3(B_), blk, 0, stream>>>(outp, outp + (long)B_ * V_);
    tails_kernel<<<dim3((M_ + 255) / 256), blk, 0, stream>>>(remF, nuF, outp + 2L * B_ * V_);
}

// Round 4
// 10854.141 us; speedup vs baseline: 1.0437x; 1.0437x over previous
//
#include <hip/hip_runtime.h>
#include <hip/hip_bf16.h>
#include <math.h>

// ---------------------------------------------------------------------------
// BabiUTransformer (Universal Transformer + ACT) on gfx950.  All float I/O fp32.
// GEMMs: split-precision bf16 MFMA (hh+lh+hl, err ~2^-18 rel). Activations are
// pre-split into hi/lo bf16 planes by their PRODUCER kernels (numerically
// identical to in-GEMM splitting, removes staging VALU + halves A traffic).
// Attention: LDS stride padded 64->65 (kills 64-way bank conflict), 4-way
// partial sums. ACT any()-gate via per-step device flag (ballot-reduced).
// Workspace ~254 MiB (same as passing round 3).
// ---------------------------------------------------------------------------

typedef unsigned short ushort_t;
using short8  = __attribute__((ext_vector_type(8))) short;
using floatx4 = __attribute__((ext_vector_type(4))) float;

#define B_   256
#define L_   71
#define H_   512
#define M_   (B_*L_)      // 18176 rows (284 x 64); half = 9088 (142 x 64)
#define MH_  9088
#define FS_  2048
#define V_   32000
#define NH_  8
#define DK_  64

__device__ inline ushort_t f2bf_rne(float f) {
    unsigned u = __float_as_uint(f);
    return (ushort_t)((u + 0x7FFFu + ((u >> 16) & 1u)) >> 16);
}

// ---------------------------------------------------------------------------
// Split GEMM: C[M,N] = alpha*(A @ B) (+bias)(+residual)(relu)
// A pre-split hi/lo bf16 planes [rows, lda]. B hi/lo planes [N,K] row-major.
// conv=1: row m's 3C window starts at A row (am+rowA-1); k-chunk d==0 invalid
//   at l==0, d==2 invalid at l==70 (zero-filled). l from (am+rowG)%71.
// outMode: 0 = f32 out; 1 = f32 out + fused prev-update; 2 = bf16 hi/lo out.
// ---------------------------------------------------------------------------
__global__ __launch_bounds__(256) void gemm_s(
    const ushort_t* __restrict__ AH, const ushort_t* __restrict__ AL,
    int lda, int conv, int rowA, int rowG,
    const ushort_t* __restrict__ Bh, const ushort_t* __restrict__ Bl,
    int N, int K,
    const float* __restrict__ bias, const float* residual,
    float alpha, int relu, int rowC, int outMode,
    float* Cout, ushort_t* CoutH, ushort_t* CoutL,
    float* prev, const float* __restrict__ uw)
{
    __shared__ short Ahs[2560], Als[2560], Bhs[2560], Bls[2560];
    const int tid  = threadIdx.x;
    const int wave = tid >> 6, lane = tid & 63;
    const int bm = blockIdx.y << 6, bn = blockIdx.x << 6;
    const int wr = (wave >> 1) << 5, wc = (wave & 1) << 5;

    floatx4 acc[2][2] = {};

    const int rowL = tid >> 2;           // 0..63
    const int ak   = (tid & 3) << 3;     // 0,8,16,24
    const int am   = bm + rowL;
    long aoffg;
    int l = 0;
    if (conv) {
        l     = (am + rowG) % 71;
        aoffg = (long)(am + rowA - 1) * lda + ak;
    } else {
        aoffg = (long)(am + rowA) * lda + ak;
    }
    const ushort_t* Aph = AH + aoffg;
    const ushort_t* Apl = AL + aoffg;
    const long bgoff = (long)(bn + rowL) * K + ak;
    const int woff = rowL * 40 + ak;

    const int quad = lane >> 4, mr = lane & 15;
    const int aoff0 = (wr + mr) * 40 + quad * 8, aoff1 = aoff0 + 640;
    const int boff0 = (wc + mr) * 40 + quad * 8, boff1 = boff0 + 640;

    for (int k0 = 0; k0 < K; k0 += 32) {
        uint4 ahv = {0,0,0,0}, alv = {0,0,0,0};
        bool valid = true;
        if (conv) {
            int kk = ak + k0;
            int d = (kk >= lda) ? ((kk >= 2 * lda) ? 2 : 1) : 0;
            valid = !((l == 0 && d == 0) || (l == 70 && d == 2));
        }
        if (valid) {
            ahv = *(const uint4*)(Aph + k0);
            alv = *(const uint4*)(Apl + k0);
        }
        uint4 bh = *(const uint4*)(Bh + bgoff + k0);
        uint4 bl = *(const uint4*)(Bl + bgoff + k0);
        __syncthreads();
        *(uint4*)(Ahs + woff) = ahv;
        *(uint4*)(Als + woff) = alv;
        *(uint4*)(Bhs + woff) = bh;
        *(uint4*)(Bls + woff) = bl;
        __syncthreads();
        short8 ah0 = *(const short8*)(Ahs + aoff0), ah1 = *(const short8*)(Ahs + aoff1);
        short8 al0 = *(const short8*)(Als + aoff0), al1 = *(const short8*)(Als + aoff1);
        short8 bh0 = *(const short8*)(Bhs + boff0), bh1 = *(const short8*)(Bhs + boff1);
        short8 bl0 = *(const short8*)(Bls + boff0), bl1 = *(const short8*)(Bls + boff1);
        acc[0][0] = __builtin_amdgcn_mfma_f32_16x16x32_bf16(ah0, bh0, acc[0][0], 0, 0, 0);
        acc[0][0] = __builtin_amdgcn_mfma_f32_16x16x32_bf16(al0, bh0, acc[0][0], 0, 0, 0);
        acc[0][0] = __builtin_amdgcn_mfma_f32_16x16x32_bf16(ah0, bl0, acc[0][0], 0, 0, 0);
        acc[0][1] = __builtin_amdgcn_mfma_f32_16x16x32_bf16(ah0, bh1, acc[0][1], 0, 0, 0);
        acc[0][1] = __builtin_amdgcn_mfma_f32_16x16x32_bf16(al0, bh1, acc[0][1], 0, 0, 0);
        acc[0][1] = __builtin_amdgcn_mfma_f32_16x16x32_bf16(ah0, bl1, acc[0][1], 0, 0, 0);
        acc[1][0] = __builtin_amdgcn_mfma_f32_16x16x32_bf16(ah1, bh0, acc[1][0], 0, 0, 0);
        acc[1][0] = __builtin_amdgcn_mfma_f32_16x16x32_bf16(al1, bh0, acc[1][0], 0, 0, 0);
        acc[1][0] = __builtin_amdgcn_mfma_f32_16x16x32_bf16(ah1, bl0, acc[1][0], 0, 0, 0);
        acc[1][1] = __builtin_amdgcn_mfma_f32_16x16x32_bf16(ah1, bh1, acc[1][1], 0, 0, 0);
        acc[1][1] = __builtin_amdgcn_mfma_f32_16x16x32_bf16(al1, bh1, acc[1][1], 0, 0, 0);
        acc[1][1] = __builtin_amdgcn_mfma_f32_16x16x32_bf16(ah1, bl1, acc[1][1], 0, 0, 0);
    }

    // C/D layout: col = lane&15, row = quad*4 + r  [verified m89/m91]
    #pragma unroll
    for (int ti = 0; ti < 2; ti++)
    #pragma unroll
    for (int tj = 0; tj < 2; tj++) {
        int gcol = bn + wc + tj * 16 + mr;
        float bv = bias ? bias[gcol] : 0.f;
        #pragma unroll
        for (int r = 0; r < 4; r++) {
            int grow = bm + wr + ti * 16 + quad * 4 + r;
            long crow = (long)grow + rowC;
            float v = acc[ti][tj][r] * alpha + bv;
            if (residual) v += residual[crow * N + gcol];
            if (relu) v = fmaxf(v, 0.f);
            long cidx = crow * (long)N + gcol;
            if (outMode == 2) {
                ushort_t h = f2bf_rne(v);
                float hf = __uint_as_float(((unsigned)h) << 16);
                CoutH[cidx] = h;
                CoutL[cidx] = f2bf_rne(v - hf);
            } else {
                Cout[cidx] = v;
                if (outMode == 1) {
                    float u = uw[crow];
                    prev[cidx] = v * u + prev[cidx] * (1.f - u);
                }
            }
        }
    }
}

// Timing-signal tables, float32 math (matches numpy float32 exp/sin chain).
__global__ __launch_bounds__(256) void sig_prep(float* __restrict__ T, float* __restrict__ P)
{
    int i = blockIdx.x * 256 + threadIdx.x;
    const int NT = 71 * 512;
    if (i >= NT + 6 * 512) return;
    int pos, c, idx;
    float* dst;
    if (i < NT) { pos = i >> 9; c = i & 511; dst = T; idx = i; }
    else        { int j = i - NT; pos = j >> 9; c = j & 511; dst = P; idx = j; }
    const float loginc = 0.036119766f;
    int jj = c & 255;
    float inv = expf(-(float)jj * loginc);
    float arg = (float)pos * inv;
    dst[idx] = (c < 256) ? sinf(arg) : cosf(arg);
}

// active-gate: flag |= any(hp<0.9 && nu<6)   (ballot, 1 atomic/wave)
__global__ __launch_bounds__(256) void gate_kernel(
    const float* __restrict__ hp, const float* __restrict__ nu, int* __restrict__ flag)
{
    int i = blockIdx.x * 256 + threadIdx.x;
    bool act = (i < M_) && (hp[i] < 0.9f) && (nu[i] < 6.0f);
    unsigned long long b = __ballot(act);
    if ((threadIdx.x & 63) == 0 && b) atomicOr(flag, 1);
}

// s = state + T[l] + P[t] (in-place); pr = sigmoid(s.p_w+p_b); gated ACT.
__global__ __launch_bounds__(256) void s_pr_kernel(
    float* trunk, const float* __restrict__ Ttab, const float* __restrict__ Ptab,
    const float* __restrict__ p_w, const float* __restrict__ p_b,
    float* __restrict__ hp, float* __restrict__ rem, float* __restrict__ nu,
    float* __restrict__ uw, const int* __restrict__ flag, int t)
{
    const int row  = blockIdx.x * 4 + (threadIdx.x >> 6);
    const int lane = threadIdx.x & 63;
    const int l    = row % 71;
    float dot = 0.f;
    #pragma unroll
    for (int j = 0; j < 8; j++) {
        int c  = lane + 64 * j;
        float sv = trunk[(long)row * H_ + c] + Ttab[l * H_ + c] + Ptab[t * H_ + c];
        trunk[(long)row * H_ + c] = sv;
        dot += sv * p_w[c];
    }
    #pragma unroll
    for (int o = 32; o; o >>= 1) dot += __shfl_xor(dot, o);
    if (lane == 0) {
        if (flag[0]) {
            float pr = 1.f / (1.f + expf(-(dot + p_b[0])));
            float hp0 = hp[row], rem0 = rem[row], nu0 = nu[row];
            float still = (hp0 < 1.0f) ? 1.f : 0.f;
            float tot   = hp0 + pr * still;
            float nh    = ((tot > 0.9f) ? 1.f : 0.f) * still;
            float st2   = ((tot <= 0.9f) ? 1.f : 0.f) * still;
            float hp2   = hp0 + pr * st2;
            float rem2  = rem0 + nh * (1.f - hp2);
            hp2 += nh * rem2;
            hp[row] = hp2; rem[row] = rem2; nu[row] = nu0 + st2 + nh;
            uw[row] = pr * st2 + nh * rem2;
        } else {
            uw[row] = 0.f;
        }
    }
}

// LayerNorm fp32 -> bf16 hi/lo planes.
__global__ __launch_bounds__(256) void ln_kernel(
    const float* __restrict__ X, const float* __restrict__ g,
    const float* __restrict__ bb, ushort_t* __restrict__ outH,
    ushort_t* __restrict__ outL)
{
    const int row  = blockIdx.x * 4 + (threadIdx.x >> 6);
    const int lane = threadIdx.x & 63;
    const float* xr = X + (long)row * H_;
    float v[8];
    float s = 0.f;
    #pragma unroll
    for (int j = 0; j < 8; j++) { v[j] = xr[lane + 64 * j]; s += v[j]; }
    #pragma unroll
    for (int o = 32; o; o >>= 1) s += __shfl_xor(s, o);
    float mean = s * (1.f / 512.f);
    float q = 0.f;
    #pragma unroll
    for (int j = 0; j < 8; j++) { float d = v[j] - mean; q += d * d; }
    #pragma unroll
    for (int o = 32; o; o >>= 1) q += __shfl_xor(q, o);
    float sd  = sqrtf(q * (1.f / 511.f));
    float inv = 1.f / (sd + 1e-6f);
    #pragma unroll
    for (int j = 0; j < 8; j++) {
        int c = lane + 64 * j;
        float val = g[c] * (v[j] - mean) * inv + bb[c];
        ushort_t h = f2bf_rne(val);
        float hf = __uint_as_float(((unsigned)h) << 16);
        long idx = (long)row * H_ + c;
        outH[idx] = h;
        outL[idx] = f2bf_rne(val - hf);
    }
}

// Attention, fp32, LDS stride 65 (conflict-free). One block per (b,h).
// q pre-scaled by 1/8 in the q-GEMM. ctx written as bf16 hi/lo planes.
__global__ __launch_bounds__(256) void attn_kernel(
    const float* __restrict__ q, const float* __restrict__ k,
    const float* __restrict__ v, ushort_t* __restrict__ ctxH,
    ushort_t* __restrict__ ctxL)
{
    __shared__ float qs[L_ * 65];
    __shared__ float ks[L_ * 65];   // reused for V
    __shared__ float Ss[L_ * L_];
    const int tid = threadIdx.x;
    const int b = blockIdx.x >> 3, h = blockIdx.x & 7;
    const long base = (long)b * L_ * H_ + h * DK_;
    for (int idx = tid; idx < L_ * DK_; idx += 256) {
        int i = idx >> 6, d = idx & 63;
        qs[i * 65 + d] = q[base + (long)i * H_ + d];
        ks[i * 65 + d] = k[base + (long)i * H_ + d];
    }
    __syncthreads();
    for (int idx = tid; idx < L_ * L_; idx += 256) {
        int i = idx / 71, j = idx % 71;
        const float* qr = qs + i * 65;
        const float* kr = ks + j * 65;
        float s0 = 0.f, s1 = 0.f, s2 = 0.f, s3 = 0.f;
        #pragma unroll
        for (int d = 0; d < 64; d += 4) {
            s0 += qr[d]     * kr[d];
            s1 += qr[d + 1] * kr[d + 1];
            s2 += qr[d + 2] * kr[d + 2];
            s3 += qr[d + 3] * kr[d + 3];
        }
        Ss[i * 71 + j] = (s0 + s1) + (s2 + s3);
    }
    __syncthreads();
    if (tid < L_) {
        float mx = -1e30f;
        for (int j = 0; j < L_; j++) mx = fmaxf(mx, Ss[tid * 71 + j]);
        float sm = 0.f;
        for (int j = 0; j < L_; j++) { float e = expf(Ss[tid * 71 + j] - mx); Ss[tid * 71 + j] = e; sm += e; }
        float inv = 1.f / sm;
        for (int j = 0; j < L_; j++) Ss[tid * 71 + j] *= inv;
    }
    for (int idx = tid; idx < L_ * DK_; idx += 256) {
        int i = idx >> 6, d = idx & 63;
        ks[i * 65 + d] = v[base + (long)i * H_ + d];
    }
    __syncthreads();
    for (int idx = tid; idx < L_ * DK_; idx += 256) {
        int i = idx >> 6, d = idx & 63;
        const float* sr = Ss + i * 71;
        float s0 = 0.f, s1 = 0.f;
        int j = 0;
        for (; j + 1 < L_; j += 2) {
            s0 += sr[j]     * ks[j * 65 + d];
            s1 += sr[j + 1] * ks[(j + 1) * 65 + d];
        }
        float s = s0 + s1 + sr[70] * ks[70 * 65 + d];
        ushort_t hh = f2bf_rne(s);
        float hf = __uint_as_float(((unsigned)hh) << 16);
        long o = base + (long)i * H_ + d;
        ctxH[o] = hh;
        ctxL[o] = f2bf_rne(s - hf);
    }
}

// Embedding -> bf16 hi/lo planes
__global__ __launch_bounds__(256) void embed_kernel(
    const int* __restrict__ story, const int* __restrict__ query,
    const float* __restrict__ emb, const float* __restrict__ mask,
    ushort_t* __restrict__ xH, ushort_t* __restrict__ xL)
{
    __shared__ int idx[11];
    const int row = blockIdx.x;
    const int b = row / 71, m = row % 71;
    const int tid = threadIdx.x;
    if (tid < 11)
        idx[tid] = (m < 70) ? story[((long)b * 70 + m) * 11 + tid]
                            : query[(long)b * 11 + tid];
    __syncthreads();
    for (int c = tid; c < H_; c += 256) {
        float acc = 0.f;
        #pragma unroll
        for (int s = 0; s < 11; s++)
            acc += emb[(long)idx[s] * H_ + c] * mask[s * H_ + c];
        ushort_t h = f2bf_rne(acc);
        float hf = __uint_as_float(((unsigned)h) << 16);
        long o = (long)row * H_ + c;
        xH[o] = h;
        xL[o] = f2bf_rne(acc - hf);
    }
}

// transpose + split fp32 [R,C] -> bf16 hi/lo planes [C,R]
__global__ __launch_bounds__(256) void wsplitT_kernel(
    const float* __restrict__ in, ushort_t* __restrict__ hi, ushort_t* __restrict__ lo,
    int R, int C)
{
    long i = (long)blockIdx.x * 256 + threadIdx.x;
    if (i < (long)R * C) {
        int r = (int)(i / C), c = (int)(i % C);
        float f = in[i];
        ushort_t h = f2bf_rne(f);
        float hf = __uint_as_float(((unsigned)h) << 16);
        hi[(long)c * R + r] = h;
        lo[(long)c * R + r] = f2bf_rne(f - hf);
    }
}

// conv weight gather+split: plane[n*(3C) + d*C + c] = w[(n*C + c)*3 + d]
__global__ __launch_bounds__(256) void convw_split_kernel(
    const float* __restrict__ w, ushort_t* __restrict__ hi, ushort_t* __restrict__ lo,
    int N, int C)
{
    long i = (long)blockIdx.x * 256 + threadIdx.x;
    if (i < (long)N * C * 3) {
        int n = (int)(i / (3 * C));
        int r = (int)(i % (3 * C));
        int d = r / C, c = r % C;
        float f = w[((long)n * C + c) * 3 + d];
        ushort_t h = f2bf_rne(f);
        float hf = __uint_as_float(((unsigned)h) << 16);
        hi[i] = h;
        lo[i] = f2bf_rne(f - hf);
    }
}

// plain split: emb [V,E] -> hi/lo planes same layout
__global__ __launch_bounds__(256) void esplit_kernel(
    const float* __restrict__ in, ushort_t* __restrict__ hi, ushort_t* __restrict__ lo,
    long n)
{
    long i = (long)blockIdx.x * 256 + threadIdx.x;
    if (i < n) {
        float f = in[i];
        ushort_t h = f2bf_rne(f);
        float hf = __uint_as_float(((unsigned)h) << 16);
        hi[i] = h;
        lo[i] = f2bf_rne(f - hf);
    }
}

__global__ __launch_bounds__(256) void zero_f32(float* __restrict__ p, long n)
{
    long i = (long)blockIdx.x * 256 + threadIdx.x;
    if (i < n) p[i] = 0.f;
}

// pooled[b,c] = (sum_l prev[b,l,c]) / 71 -> bf16 hi/lo planes
__global__ __launch_bounds__(256) void pooled_kernel(
    const float* __restrict__ prev, ushort_t* __restrict__ pH, ushort_t* __restrict__ pL)
{
    int i = blockIdx.x * 256 + threadIdx.x;   // [0, 256*512)
    int b = i >> 9, c = i & 511;
    float s = 0.f;
    for (int l = 0; l < L_; l++) s += prev[((long)b * L_ + l) * H_ + c];
    float p = s / 71.0f;
    ushort_t h = f2bf_rne(p);
    float hf = __uint_as_float(((unsigned)h) << 16);
    pH[i] = h;
    pL[i] = f2bf_rne(p - hf);
}

__global__ __launch_bounds__(256) void softmax_kernel(
    const float* __restrict__ ah, float* __restrict__ out)
{
    __shared__ float red[256];
    const int b = blockIdx.x, tid = threadIdx.x;
    const float* a = ah + (long)b * V_;
    float mx = -1e30f;
    for (int i = tid; i < V_; i += 256) mx = fmaxf(mx, a[i]);
    red[tid] = mx; __syncthreads();
    for (int o = 128; o; o >>= 1) { if (tid < o) red[tid] = fmaxf(red[tid], red[tid + o]); __syncthreads(); }
    mx = red[0]; __syncthreads();
    float s = 0.f;
    for (int i = tid; i < V_; i += 256) s += expf(a[i] - mx);
    red[tid] = s; __syncthreads();
    for (int o = 128; o; o >>= 1) { if (tid < o) red[tid] += red[tid + o]; __syncthreads(); }
    float inv = 1.f / red[0];
    float* o_ = out + (long)b * V_;
    for (int i = tid; i < V_; i += 256) o_[i] = expf(a[i] - mx) * inv;
}

__global__ __launch_bounds__(256) void tails_kernel(
    const float* __restrict__ rem, const float* __restrict__ nu, float* __restrict__ out)
{
    int i = blockIdx.x * 256 + threadIdx.x;
    if (i < M_) {
        out[i] = rem[i];
        out[M_ + i] = nu[i];
    }
}

// ---------------------------------------------------------------------------
extern "C" void kernel_launch(void* const* d_in, const int* in_sizes, int n_in,
                              void* d_out, int out_size, void* d_ws, size_t ws_size,
                              hipStream_t stream)
{
    const int*   story  = (const int*)d_in[0];
    const int*   query  = (const int*)d_in[1];
    const float* emb    = (const float*)d_in[2];
    const float* mask_p = (const float*)d_in[3];
    const float* proj_w = (const float*)d_in[4];
    const float* ln1_g  = (const float*)d_in[5];
    const float* ln1_b  = (const float*)d_in[6];
    const float* wq     = (const float*)d_in[7];
    const float* wk     = (const float*)d_in[8];
    const float* wv     = (const float*)d_in[9];
    const float* wo     = (const float*)d_in[10];
    const float* c1_w   = (const float*)d_in[11];
    const float* c1_b   = (const float*)d_in[12];
    const float* c2_w   = (const float*)d_in[13];
    const float* c2_b   = (const float*)d_in[14];
    const float* ln2_g  = (const float*)d_in[15];
    const float* ln2_b  = (const float*)d_in[16];
    const float* p_w    = (const float*)d_in[17];
    const float* p_b    = (const float*)d_in[18];
    const float* out_b  = (const float*)d_in[19];
    float* outp = (float*)d_out;

    char* wsb = (char*)d_ws;
    size_t off = 0;
    auto alloc = [&](size_t bytes) -> void* {
        void* p = wsb + off;
        off = (off + bytes + 255) & ~(size_t)255;
        return p;
    };
    const long ROWE = (long)M_ * H_;             // 9,306,112 elements

    float* trunkF = (float*)alloc(ROWE * 4);
    float* prevF  = (float*)alloc(ROWE * 4);
    char*  poolC  = (char*)alloc(4L * ROWE * 4); // 148.9 MB multi-purpose pool
    float* hpF    = (float*)alloc((long)M_ * 4 * 4 + 64);
    float* remF   = hpF + M_;
    float* nuF    = hpF + 2 * M_;
    float* uwF    = hpF + 3 * M_;
    int*   flags  = (int*)(hpF + 4 * M_);
    ushort_t* projH = (ushort_t*)alloc((long)H_ * H_ * 2);
    ushort_t* projL = (ushort_t*)alloc((long)H_ * H_ * 2);
    ushort_t* wqH   = (ushort_t*)alloc((long)H_ * H_ * 2);
    ushort_t* wqL   = (ushort_t*)alloc((long)H_ * H_ * 2);
    ushort_t* wkH   = (ushort_t*)alloc((long)H_ * H_ * 2);
    ushort_t* wkL   = (ushort_t*)alloc((long)H_ * H_ * 2);
    ushort_t* wvH   = (ushort_t*)alloc((long)H_ * H_ * 2);
    ushort_t* wvL   = (ushort_t*)alloc((long)H_ * H_ * 2);
    ushort_t* woH   = (ushort_t*)alloc((long)H_ * H_ * 2);
    ushort_t* woL   = (ushort_t*)alloc((long)H_ * H_ * 2);
    ushort_t* W1H   = (ushort_t*)alloc((long)FS_ * 3 * H_ * 2);
    ushort_t* W1L   = (ushort_t*)alloc((long)FS_ * 3 * H_ * 2);
    ushort_t* W2H   = (ushort_t*)alloc((long)H_ * 3 * FS_ * 2);
    ushort_t* W2L   = (ushort_t*)alloc((long)H_ * 3 * FS_ * 2);
    ushort_t* pooledH = (ushort_t*)alloc((long)B_ * H_ * 2);
    ushort_t* pooledL = (ushort_t*)alloc((long)B_ * H_ * 2);
    float* Ttab     = (float*)alloc((long)L_ * H_ * 4);
    float* Ptab     = (float*)alloc(6L * H_ * 4);

    // pool aliases (phases disjoint in time):
    //   phase A (qkv+attn+wo): xnH|xnL (ctx reuses) + qb + kb + vb
    //   phase B (convs):       xn2H|xn2L + y1H|y1L (half)
    //   pre-loop: xembH|xembL ; post-loop: embH|embL
    ushort_t* xnH = (ushort_t*)poolC;
    ushort_t* xnL = xnH + ROWE;
    float* qbF = (float*)(poolC + ROWE * 4);
    float* kbF = qbF + ROWE;
    float* vbF = qbF + 2 * ROWE;
    ushort_t* ctxH = xnH;
    ushort_t* ctxL = xnL;
    ushort_t* xn2H = (ushort_t*)poolC;
    ushort_t* xn2L = xn2H + ROWE;
    ushort_t* y1H  = (ushort_t*)(poolC + ROWE * 4);
    ushort_t* y1L  = y1H + (long)MH_ * FS_;
    ushort_t* xembH = (ushort_t*)poolC;
    ushort_t* xembL = xembH + ROWE;
    ushort_t* embH = (ushort_t*)poolC;
    ushort_t* embL = embH + (long)V_ * H_;

    dim3 blk(256);

    // --- init (ws re-poisoned every call) ---
    zero_f32<<<dim3((unsigned)((ROWE + 255) / 256)), blk, 0, stream>>>(prevF, ROWE);
    zero_f32<<<dim3((3 * M_ + 255) / 256), blk, 0, stream>>>(hpF, 3 * M_);
    zero_f32<<<dim3(1), blk, 0, stream>>>((float*)flags, 16);
    sig_prep<<<dim3(154), blk, 0, stream>>>(Ttab, Ptab);

    // --- weight prep: transpose + hi/lo split ---
    wsplitT_kernel<<<dim3(1024), blk, 0, stream>>>(proj_w, projH, projL, H_, H_);
    wsplitT_kernel<<<dim3(1024), blk, 0, stream>>>(wq, wqH, wqL, H_, H_);
    wsplitT_kernel<<<dim3(1024), blk, 0, stream>>>(wk, wkH, wkL, H_, H_);
    wsplitT_kernel<<<dim3(1024), blk, 0, stream>>>(wv, wvH, wvL, H_, H_);
    wsplitT_kernel<<<dim3(1024), blk, 0, stream>>>(wo, woH, woL, H_, H_);
    convw_split_kernel<<<dim3(12288), blk, 0, stream>>>(c1_w, W1H, W1L, FS_, H_);
    convw_split_kernel<<<dim3(12288), blk, 0, stream>>>(c2_w, W2H, W2L, H_, FS_);

    // --- embedding + input projection ---
    embed_kernel<<<dim3(M_), blk, 0, stream>>>(story, query, emb, mask_p, xembH, xembL);
    gemm_s<<<dim3(H_ / 64, M_ / 64), blk, 0, stream>>>(
        xembH, xembL, H_, 0, 0, 0, projH, projL, H_, H_,
        nullptr, nullptr, 1.f, 0, 0, 0, trunkF, nullptr, nullptr, nullptr, nullptr);

    // --- ACT loop: 6 steps with faithful any()-gate ---
    for (int t = 0; t < 6; t++) {
        gate_kernel<<<dim3(M_ / 256), blk, 0, stream>>>(hpF, nuF, flags + t);
        s_pr_kernel<<<dim3(M_ / 4), blk, 0, stream>>>(trunkF, Ttab, Ptab, p_w, p_b,
                                                      hpF, remF, nuF, uwF, flags + t, t);
        ln_kernel<<<dim3(M_ / 4), blk, 0, stream>>>(trunkF, ln1_g, ln1_b, xnH, xnL);
        gemm_s<<<dim3(H_ / 64, M_ / 64), blk, 0, stream>>>(
            xnH, xnL, H_, 0, 0, 0, wqH, wqL, H_, H_,
            nullptr, nullptr, 0.125f, 0, 0, 0, qbF, nullptr, nullptr, nullptr, nullptr);
        gemm_s<<<dim3(H_ / 64, M_ / 64), blk, 0, stream>>>(
            xnH, xnL, H_, 0, 0, 0, wkH, wkL, H_, H_,
            nullptr, nullptr, 1.f, 0, 0, 0, kbF, nullptr, nullptr, nullptr, nullptr);
        gemm_s<<<dim3(H_ / 64, M_ / 64), blk, 0, stream>>>(
            xnH, xnL, H_, 0, 0, 0, wvH, wvL, H_, H_,
            nullptr, nullptr, 1.f, 0, 0, 0, vbF, nullptr, nullptr, nullptr, nullptr);
        attn_kernel<<<dim3(B_ * NH_), blk, 0, stream>>>(qbF, kbF, vbF, ctxH, ctxL);
        gemm_s<<<dim3(H_ / 64, M_ / 64), blk, 0, stream>>>(
            ctxH, ctxL, H_, 0, 0, 0, woH, woL, H_, H_,
            nullptr, trunkF, 1.f, 0, 0, 0, trunkF, nullptr, nullptr, nullptr, nullptr);
        ln_kernel<<<dim3(M_ / 4), blk, 0, stream>>>(trunkF, ln2_g, ln2_b, xn2H, xn2L);
        for (int half = 0; half < 2; half++) {
            int ro = half * MH_;
            gemm_s<<<dim3(FS_ / 64, MH_ / 64), blk, 0, stream>>>(
                xn2H, xn2L, H_, 1, ro, ro, W1H, W1L, FS_, 3 * H_,
                c1_b, nullptr, 1.f, 1, 0, 2, nullptr, y1H, y1L, nullptr, nullptr);
            gemm_s<<<dim3(H_ / 64, MH_ / 64), blk, 0, stream>>>(
                y1H, y1L, FS_, 1, 0, ro, W2H, W2L, H_, 3 * FS_,
                c2_b, trunkF, 1.f, 0, ro, 1, trunkF, nullptr, nullptr, prevF, uwF);
        }
    }

    // --- output head ---
    pooled_kernel<<<dim3(B_ * H_ / 256), blk, 0, stream>>>(prevF, pooledH, pooledL);
    esplit_kernel<<<dim3(64000), blk, 0, stream>>>(emb, embH, embL, (long)V_ * H_);
    gemm_s<<<dim3(V_ / 64, B_ / 64), blk, 0, stream>>>(
        pooledH, pooledL, H_, 0, 0, 0, embH, embL, V_, H_,
        out_b, nullptr, 1.f, 0, 0, 0, outp, nullptr, nullptr, nullptr, nullptr);
    softmax_kernel<<<dim3(B_), blk, 0, stream>>>(outp, outp + (long)B_ * V_);
    tails_kernel<<<dim3((M_ + 255) / 256), blk, 0, stream>>>(remF, nuF, outp + 2L * B_ * V_);
}